// Round 6
// baseline (52.299 us; speedup 1.0000x reference)
//
#include <hip/hip_runtime.h>
#include <math.h>

// NonLinearReadoutBlock, round 6: r3 MFMA structure, register-budgeted for
// occupancy. B fragments + layer-2 weights live in LDS (pre-packed in exact
// fragment layout -> conflict-free ds_read_b128). Tile processed in 4
// kb-granules using two alternating 8xfloat4 buffers (64 VGPR total for
// loads); each granule's registers are reissued for granule+2 right after
// conversion (guarded prefetch, no redundant fetch). Target <=128 VGPR,
// launch_bounds(256,4), grid 1024 -> 16 waves/CU.

typedef short bf16x8 __attribute__((ext_vector_type(8)));
typedef int   i32x4  __attribute__((ext_vector_type(4)));
typedef float f32x4  __attribute__((ext_vector_type(4)));

static __device__ __forceinline__ short f2bf(float f) {
    union { float f; unsigned u; } v; v.f = f;
    return (short)((v.u + 0x8000u) >> 16);
}
static __device__ __forceinline__ unsigned cvtpk(float lo, float hi) {
    unsigned r;
    asm("v_cvt_pk_bf16_f32 %0, %1, %2" : "=v"(r) : "v"(lo), "v"(hi));
    return r;   // {lo16: bf16(lo), hi16: bf16(hi)}
}

#define BLOCK 256

__global__ __launch_bounds__(BLOCK, 4) void nlrb_kernel(
    const float* __restrict__ x,
    const float* __restrict__ W1s,   // (128,32)
    const float* __restrict__ W1v,   // (128,16)
    const float* __restrict__ b1s,   // (32)
    const float* __restrict__ W2s,   // (16,10)
    const float* __restrict__ W2v,   // (16)
    const float* __restrict__ b2s,   // (10)
    float* __restrict__ out,         // (N,13)
    int N)
{
    // B fragments pre-packed as [kb][mq][o] bf16x8: a wave's ds_read_b128 at
    // fixed kb covers bytes [0,1024) exactly once -> conflict-free.
    __shared__ bf16x8 BS0[4][4][16];   // 4 KB
    __shared__ bf16x8 BS1[4][4][16];   // 4 KB
    __shared__ bf16x8 BVv[4][4][16];   // 4 KB
    __shared__ float  WC[16][20];      // layer-2 weights [e][j], stride 20
    __shared__ float  sred[4][16][68]; // wave-private layer-2 operands

    const int tid  = threadIdx.x;
    const int wave = tid >> 6;
    const int lane = tid & 63;
    const int mq   = lane >> 4;
    const int o    = lane & 15;
    const float inv1 = 0.08838834764831843f;  // 1/sqrt(128)

    // ---- one-time staging of weights into LDS ----
    {
        const int kb = tid >> 6, m = (tid >> 4) & 3, oo = tid & 15;
        bf16x8 t0, t1, t2;
        #pragma unroll
        for (int j = 0; j < 8; ++j) {
            const int k = kb * 32 + m * 8 + j;
            t0[j] = f2bf(W1s[k * 32 + oo]);
            t1[j] = f2bf(W1s[k * 32 + 16 + oo]);
            t2[j] = f2bf(W1v[k * 16 + oo]);
        }
        BS0[kb][m][oo] = t0;
        BS1[kb][m][oo] = t1;
        BVv[kb][m][oo] = t2;
        if (tid < 16) {
            #pragma unroll
            for (int j = 0; j < 16; ++j)
                WC[tid][j] = (tid < 10) ? W2s[j * 10 + tid] : W2v[j];
        }
    }
    __syncthreads();

    const float b1a = b1s[o];
    const float b1b = b1s[16 + o];
    const float b2e = (o < 10) ? b2s[o] : 0.0f;

    const int NT = N >> 4;                  // 6250 tiles
    const int wstride = gridDim.x << 2;
    const int wt0 = (blockIdx.x << 2) + wave;
    const size_t pfoff = (size_t)wstride * 8192;   // next-tile addr delta (floats)

// issue one kb-granule (8 float4 = 32 VGPR) for row o, chunk mq
#define ISSUE(A, xp, kb)                                                     \
    do {                                                                     \
        A[0] = *(const float4*)((xp) + (kb) * 32 + mq * 8);                  \
        A[1] = *(const float4*)((xp) + (kb) * 32 + mq * 8 + 4);              \
        _Pragma("unroll")                                                    \
        for (int q = 0; q < 6; ++q)                                          \
            A[2 + q] = *(const float4*)((xp) + 128 + (kb) * 96 + mq * 24 + q * 4); \
    } while (0)

// convert granule -> 4 bf16x8 fragments (cvt_pk + v_perm stride-3 split)
#define CONV(A, aS, a0, a1, a2)                                              \
    do {                                                                     \
        i32x4 ws;                                                            \
        ws[0] = (int)cvtpk(A[0].x, A[0].y); ws[1] = (int)cvtpk(A[0].z, A[0].w); \
        ws[2] = (int)cvtpk(A[1].x, A[1].y); ws[3] = (int)cvtpk(A[1].z, A[1].w); \
        aS = __builtin_bit_cast(bf16x8, ws);                                 \
        unsigned p[12];                                                      \
        _Pragma("unroll")                                                    \
        for (int q = 0; q < 6; ++q) {                                        \
            p[2 * q]     = cvtpk(A[2 + q].x, A[2 + q].y);                    \
            p[2 * q + 1] = cvtpk(A[2 + q].z, A[2 + q].w);                    \
        }                                                                    \
        i32x4 w0, w1, w2;                                                    \
        _Pragma("unroll")                                                    \
        for (int w = 0; w < 4; ++w) {                                        \
            w0[w] = (int)__builtin_amdgcn_perm(p[3*w+1], p[3*w],   0x07060100u); \
            w1[w] = (int)__builtin_amdgcn_perm(p[3*w+2], p[3*w],   0x05040302u); \
            w2[w] = (int)__builtin_amdgcn_perm(p[3*w+2], p[3*w+1], 0x07060100u); \
        }                                                                    \
        a0 = __builtin_bit_cast(bf16x8, w0);                                 \
        a1 = __builtin_bit_cast(bf16x8, w1);                                 \
        a2 = __builtin_bit_cast(bf16x8, w2);                                 \
    } while (0)

// 5 MFMAs for one kb; B fragments read from LDS (conflict-free b128)
#define MF(kb, aS, a0, a1, a2)                                               \
    do {                                                                     \
        const bf16x8 q0 = BS0[kb][mq][o];                                    \
        const bf16x8 q1 = BS1[kb][mq][o];                                    \
        const bf16x8 q2 = BVv[kb][mq][o];                                    \
        accS0 = __builtin_amdgcn_mfma_f32_16x16x32_bf16(aS, q0, accS0, 0, 0, 0); \
        accS1 = __builtin_amdgcn_mfma_f32_16x16x32_bf16(aS, q1, accS1, 0, 0, 0); \
        accV0 = __builtin_amdgcn_mfma_f32_16x16x32_bf16(a0, q2, accV0, 0, 0, 0); \
        accV1 = __builtin_amdgcn_mfma_f32_16x16x32_bf16(a1, q2, accV1, 0, 0, 0); \
        accV2 = __builtin_amdgcn_mfma_f32_16x16x32_bf16(a2, q2, accV2, 0, 0, 0); \
    } while (0)

    float4 A0[8], A1[8];
    if (wt0 < NT) {
        const float* xp = x + (size_t)((wt0 << 4) + o) * 512;
        ISSUE(A0, xp, 0);
        ISSUE(A1, xp, 1);
    }

    for (int wt = wt0; wt < NT; wt += wstride) {
        const int base = wt << 4;
        const float* xp = x + (size_t)(base + o) * 512;
        const bool pf = (wt + wstride) < NT;
        const float* xq = xp + pfoff;

        f32x4 accS0 = {0.f,0.f,0.f,0.f}, accS1 = {0.f,0.f,0.f,0.f};
        f32x4 accV0 = {0.f,0.f,0.f,0.f}, accV1 = {0.f,0.f,0.f,0.f};
        f32x4 accV2 = {0.f,0.f,0.f,0.f};
        bf16x8 aS, a0, a1, a2;

        // step 0: consume kb0, reissue regs for kb2
        CONV(A0, aS, a0, a1, a2);
        ISSUE(A0, xp, 2);
        MF(0, aS, a0, a1, a2);
        // step 1: consume kb1, reissue for kb3
        CONV(A1, aS, a0, a1, a2);
        ISSUE(A1, xp, 3);
        MF(1, aS, a0, a1, a2);
        // step 2: consume kb2, prefetch next tile kb0
        CONV(A0, aS, a0, a1, a2);
        if (pf) ISSUE(A0, xq, 0);
        MF(2, aS, a0, a1, a2);
        // step 3: consume kb3, prefetch next tile kb1
        CONV(A1, aS, a0, a1, a2);
        if (pf) ISSUE(A1, xq, 1);
        MF(3, aS, a0, a1, a2);

        // ---- epilogue: lane-local silu + gating -> sred ----
        #pragma unroll
        for (int v = 0; v < 4; ++v) {
            const float hs = fmaf(accS0[v], inv1, b1a);
            const float hg = fmaf(accS1[v], inv1, b1b);
            const float s  = hs / (1.f + __expf(-hs));
            const float g  = hg / (1.f + __expf(-hg));
            const float gm = g * inv1;
            const int  r   = mq * 4 + v;
            sred[wave][r][o]      = s;
            sred[wave][r][16 + o] = gm * accV0[v];
            sred[wave][r][32 + o] = gm * accV1[v];
            sred[wave][r][48 + o] = gm * accV2[v];
        }
        asm volatile("s_waitcnt lgkmcnt(0)" ::: "memory");

        // ---- layer 2: lane o<13, dot-16 for rows mq, mq+4, mq+8, mq+12 ----
        #pragma unroll
        for (int w = 0; w < 4; ++w) {
            const int r = (w << 2) + mq;
            if (o < 13) {
                const int slot = (o < 10) ? 0 : (o - 9);
                const float* sp = &sred[wave][r][slot * 16];
                float sum = 0.f;
                #pragma unroll
                for (int q = 0; q < 4; ++q) {
                    const float4 pv = *(const float4*)(sp + q * 4);
                    const float4 wv = *(const float4*)(&WC[o][q * 4]);
                    sum = fmaf(pv.x, wv.x, sum);
                    sum = fmaf(pv.y, wv.y, sum);
                    sum = fmaf(pv.z, wv.z, sum);
                    sum = fmaf(pv.w, wv.w, sum);
                }
                out[(size_t)(base + r) * 13 + o] = fmaf(sum, 0.25f, b2e);
            }
        }
        asm volatile("s_waitcnt lgkmcnt(0)" ::: "memory");  // sred reads done
    }
#undef ISSUE
#undef CONV
#undef MF
}

extern "C" void kernel_launch(void* const* d_in, const int* in_sizes, int n_in,
                              void* d_out, int out_size, void* d_ws, size_t ws_size,
                              hipStream_t stream) {
    const float* x   = (const float*)d_in[0];
    const float* W1s = (const float*)d_in[1];
    const float* W1v = (const float*)d_in[2];
    const float* b1s = (const float*)d_in[3];
    const float* W2s = (const float*)d_in[4];
    const float* W2v = (const float*)d_in[5];
    const float* b2s = (const float*)d_in[6];
    float* outp = (float*)d_out;
    const int N = in_sizes[0] / 512;   // 100000
    nlrb_kernel<<<dim3(1024), dim3(BLOCK), 0, stream>>>(
        x, W1s, W1v, b1s, W2s, W2v, b2s, outp, N);
}

// Round 7
// 46.279 us; speedup vs baseline: 1.1301x; 1.1301x over previous
//
#include <hip/hip_runtime.h>
#include <math.h>

// NonLinearReadoutBlock, round 7: r3 MFMA structure at true <=128 VGPR.
// - B fragments + layer-2 weights in LDS, read IN-LOOP via a laundered index
//   (asm "+v" on a zero) so the compiler cannot hoist them into registers
//   (r6's failure: hoist -> forced spills under launch_bounds(256,4)).
// - Half-tile bursts: 16 float4 load regs (64 VGPR) instead of 32 (128).
// - launch_bounds(256,4): 16 waves/CU (2x round-3 occupancy), grid 1024.

typedef short bf16x8 __attribute__((ext_vector_type(8)));
typedef int   i32x4  __attribute__((ext_vector_type(4)));
typedef float f32x4  __attribute__((ext_vector_type(4)));

static __device__ __forceinline__ short f2bf(float f) {
    union { float f; unsigned u; } v; v.f = f;
    return (short)((v.u + 0x8000u) >> 16);
}
static __device__ __forceinline__ unsigned cvtpk(float lo, float hi) {
    unsigned r;
    asm("v_cvt_pk_bf16_f32 %0, %1, %2" : "=v"(r) : "v"(lo), "v"(hi));
    return r;   // {lo16: bf16(lo), hi16: bf16(hi)}
}

#define BLOCK 256

__global__ __launch_bounds__(BLOCK, 4) void nlrb_kernel(
    const float* __restrict__ x,
    const float* __restrict__ W1s,   // (128,32)
    const float* __restrict__ W1v,   // (128,16)
    const float* __restrict__ b1s,   // (32)
    const float* __restrict__ W2s,   // (16,10)
    const float* __restrict__ W2v,   // (16)
    const float* __restrict__ b2s,   // (10)
    float* __restrict__ out,         // (N,13)
    int N)
{
    // B fragments pre-packed [kb][mq][o]: wave's b128 read at fixed kb covers
    // 1024 contiguous bytes, one 16B slot per lane -> conflict-free.
    __shared__ __align__(16) bf16x8 BS0[4][4][16];   // 4 KB
    __shared__ __align__(16) bf16x8 BS1[4][4][16];   // 4 KB
    __shared__ __align__(16) bf16x8 BVv[4][4][16];   // 4 KB
    __shared__ __align__(16) float  WC[16][20];      // [e][j], 80B rows (16B-mult)
    __shared__ __align__(16) float  sred[4][16][68]; // wave-private L2 operands

    const int tid  = threadIdx.x;
    const int wave = tid >> 6;
    const int lane = tid & 63;
    const int mq   = lane >> 4;
    const int o    = lane & 15;
    const float inv1 = 0.08838834764831843f;  // 1/sqrt(128)

    // ---- one-time staging of weights into LDS ----
    {
        const int kb = tid >> 6, m = (tid >> 4) & 3, oo = tid & 15;
        bf16x8 t0, t1, t2;
        #pragma unroll
        for (int j = 0; j < 8; ++j) {
            const int k = kb * 32 + m * 8 + j;
            t0[j] = f2bf(W1s[k * 32 + oo]);
            t1[j] = f2bf(W1s[k * 32 + 16 + oo]);
            t2[j] = f2bf(W1v[k * 16 + oo]);
        }
        BS0[kb][m][oo] = t0;
        BS1[kb][m][oo] = t1;
        BVv[kb][m][oo] = t2;
        if (tid < 16) {
            #pragma unroll
            for (int j = 0; j < 16; ++j)
                WC[tid][j] = (tid < 10) ? W2s[j * 10 + tid] : W2v[j];
        }
    }
    __syncthreads();

    const float b1a = b1s[o];
    const float b1b = b1s[16 + o];
    const float b2e = (o < 10) ? b2s[o] : 0.0f;

    const int NT = N >> 4;                  // 6250 tiles
    const int wstride = gridDim.x << 2;

// issue one kb-granule (8 float4) into (S0,S1,V[6]) for row o, chunk mq
#define ISSUE_KB(S, V, xp, kb)                                               \
    do {                                                                     \
        S[0] = *(const float4*)((xp) + (kb) * 32 + mq * 8);                  \
        S[1] = *(const float4*)((xp) + (kb) * 32 + mq * 8 + 4);              \
        _Pragma("unroll")                                                    \
        for (int q = 0; q < 6; ++q)                                          \
            V[q] = *(const float4*)((xp) + 128 + (kb) * 96 + mq * 24 + q * 4); \
    } while (0)

// convert granule -> 4 bf16x8 fragments (cvt_pk + v_perm stride-3 split)
#define CONV_KB(S, V, aS, a0, a1, a2)                                        \
    do {                                                                     \
        i32x4 ws;                                                            \
        ws[0] = (int)cvtpk(S[0].x, S[0].y); ws[1] = (int)cvtpk(S[0].z, S[0].w); \
        ws[2] = (int)cvtpk(S[1].x, S[1].y); ws[3] = (int)cvtpk(S[1].z, S[1].w); \
        aS = __builtin_bit_cast(bf16x8, ws);                                 \
        unsigned p[12];                                                      \
        _Pragma("unroll")                                                    \
        for (int q = 0; q < 6; ++q) {                                        \
            p[2 * q]     = cvtpk(V[q].x, V[q].y);                            \
            p[2 * q + 1] = cvtpk(V[q].z, V[q].w);                            \
        }                                                                    \
        i32x4 w0, w1, w2;                                                    \
        _Pragma("unroll")                                                    \
        for (int w = 0; w < 4; ++w) {                                        \
            w0[w] = (int)__builtin_amdgcn_perm(p[3*w+1], p[3*w],   0x07060100u); \
            w1[w] = (int)__builtin_amdgcn_perm(p[3*w+2], p[3*w],   0x05040302u); \
            w2[w] = (int)__builtin_amdgcn_perm(p[3*w+2], p[3*w+1], 0x07060100u); \
        }                                                                    \
        a0 = __builtin_bit_cast(bf16x8, w0);                                 \
        a1 = __builtin_bit_cast(bf16x8, w1);                                 \
        a2 = __builtin_bit_cast(bf16x8, w2);                                 \
    } while (0)

// 5 MFMAs for one kb; B fragments from LDS via laundered index oz (no hoist)
#define MF_KB(kb, aS, a0, a1, a2)                                            \
    do {                                                                     \
        const bf16x8 q0 = BS0[kb][mq][oz];                                   \
        const bf16x8 q1 = BS1[kb][mq][oz];                                   \
        const bf16x8 q2 = BVv[kb][mq][oz];                                   \
        accS0 = __builtin_amdgcn_mfma_f32_16x16x32_bf16(aS, q0, accS0, 0, 0, 0); \
        accS1 = __builtin_amdgcn_mfma_f32_16x16x32_bf16(aS, q1, accS1, 0, 0, 0); \
        accV0 = __builtin_amdgcn_mfma_f32_16x16x32_bf16(a0, q2, accV0, 0, 0, 0); \
        accV1 = __builtin_amdgcn_mfma_f32_16x16x32_bf16(a1, q2, accV1, 0, 0, 0); \
        accV2 = __builtin_amdgcn_mfma_f32_16x16x32_bf16(a2, q2, accV2, 0, 0, 0); \
    } while (0)

    for (int wt = (blockIdx.x << 2) + wave; wt < NT; wt += wstride) {
        const int base = wt << 4;
        const float* xp = x + (size_t)(base + o) * 512;

        // laundered zero: LDS weight reads can't be hoisted out of the loop
        unsigned z = 0;
        asm volatile("" : "+v"(z));
        const int oz = (o + (int)z) & 15;    // == o, but opaque to compiler

        f32x4 accS0 = {0.f,0.f,0.f,0.f}, accS1 = {0.f,0.f,0.f,0.f};
        f32x4 accV0 = {0.f,0.f,0.f,0.f}, accV1 = {0.f,0.f,0.f,0.f};
        f32x4 accV2 = {0.f,0.f,0.f,0.f};
        bf16x8 aS, a0, a1, a2;

        float4 S0[2], S1[2], V0[6], V1[6];

        // ---- half 0: burst kb0+kb1 (16 loads), then consume ----
        ISSUE_KB(S0, V0, xp, 0);
        ISSUE_KB(S1, V1, xp, 1);
        CONV_KB(S0, V0, aS, a0, a1, a2);
        MF_KB(0, aS, a0, a1, a2);
        CONV_KB(S1, V1, aS, a0, a1, a2);
        MF_KB(1, aS, a0, a1, a2);

        // ---- half 1: burst kb2+kb3, then consume ----
        ISSUE_KB(S0, V0, xp, 2);
        ISSUE_KB(S1, V1, xp, 3);
        CONV_KB(S0, V0, aS, a0, a1, a2);
        MF_KB(2, aS, a0, a1, a2);
        CONV_KB(S1, V1, aS, a0, a1, a2);
        MF_KB(3, aS, a0, a1, a2);

        // ---- epilogue: lane-local silu + gating -> sred ----
        #pragma unroll
        for (int v = 0; v < 4; ++v) {
            const float hs = fmaf(accS0[v], inv1, b1a);
            const float hg = fmaf(accS1[v], inv1, b1b);
            const float s  = hs / (1.f + __expf(-hs));
            const float g  = hg / (1.f + __expf(-hg));
            const float gm = g * inv1;
            const int  r   = mq * 4 + v;
            sred[wave][r][o]      = s;
            sred[wave][r][16 + o] = gm * accV0[v];
            sred[wave][r][32 + o] = gm * accV1[v];
            sred[wave][r][48 + o] = gm * accV2[v];
        }
        asm volatile("s_waitcnt lgkmcnt(0)" ::: "memory");

        // ---- layer 2: lane o<13, dot-16 for rows mq, mq+4, mq+8, mq+12 ----
        #pragma unroll
        for (int w = 0; w < 4; ++w) {
            const int r = (w << 2) + mq;
            if (o < 13) {
                const int slot = (o < 10) ? 0 : (o - 9);
                const float* sp = &sred[wave][r][slot * 16];
                float sum = 0.f;
                #pragma unroll
                for (int q = 0; q < 4; ++q) {
                    const float4 pv = *(const float4*)(sp + q * 4);
                    const float4 wv = *(const float4*)(&WC[oz][q * 4]);
                    sum = fmaf(pv.x, wv.x, sum);
                    sum = fmaf(pv.y, wv.y, sum);
                    sum = fmaf(pv.z, wv.z, sum);
                    sum = fmaf(pv.w, wv.w, sum);
                }
                out[(size_t)(base + r) * 13 + o] = fmaf(sum, 0.25f, b2e);
            }
        }
        asm volatile("s_waitcnt lgkmcnt(0)" ::: "memory");  // sred reads done
    }
#undef ISSUE_KB
#undef CONV_KB
#undef MF_KB
}

extern "C" void kernel_launch(void* const* d_in, const int* in_sizes, int n_in,
                              void* d_out, int out_size, void* d_ws, size_t ws_size,
                              hipStream_t stream) {
    const float* x   = (const float*)d_in[0];
    const float* W1s = (const float*)d_in[1];
    const float* W1v = (const float*)d_in[2];
    const float* b1s = (const float*)d_in[3];
    const float* W2s = (const float*)d_in[4];
    const float* W2v = (const float*)d_in[5];
    const float* b2s = (const float*)d_in[6];
    float* outp = (float*)d_out;
    const int N = in_sizes[0] / 512;   // 100000
    nlrb_kernel<<<dim3(1024), dim3(BLOCK), 0, stream>>>(
        x, W1s, W1v, b1s, W2s, W2v, b2s, outp, N);
}

// Round 8
// 40.208 us; speedup vs baseline: 1.3007x; 1.1510x over previous
//
#include <hip/hip_runtime.h>
#include <math.h>

// NonLinearReadoutBlock, round 8: r5's pipelined structure with the redundant-
// fetch bug removed. Main loop prefetches next tile unconditionally into the
// same load registers right after each granule's conversion; the final tile is
// PEELED into a no-prefetch body (no clamp re-fetch, no in-loop branches).
// Resident B fragments in VGPRs, cvt_pk+v_perm conversion, wave-private LDS
// for layer 2 only. launch_bounds(256,2), grid 512 (all waves resident).

typedef short  bf16x8 __attribute__((ext_vector_type(8)));
typedef int    i32x4  __attribute__((ext_vector_type(4)));
typedef float  f32x4  __attribute__((ext_vector_type(4)));

static __device__ __forceinline__ short f2bf(float f) {
    union { float f; unsigned u; } v; v.f = f;
    return (short)((v.u + 0x8000u) >> 16);
}
static __device__ __forceinline__ unsigned cvtpk(float lo, float hi) {
    unsigned r;
    asm("v_cvt_pk_bf16_f32 %0, %1, %2" : "=v"(r) : "v"(lo), "v"(hi));
    return r;   // {lo16: bf16(lo), hi16: bf16(hi)}
}

#define BLOCK 256

__global__ __launch_bounds__(BLOCK, 2) void nlrb_kernel(
    const float* __restrict__ x,
    const float* __restrict__ W1s,   // (128,32)
    const float* __restrict__ W1v,   // (128,16)
    const float* __restrict__ b1s,   // (32)
    const float* __restrict__ W2s,   // (16,10)
    const float* __restrict__ W2v,   // (16)
    const float* __restrict__ b2s,   // (10)
    float* __restrict__ out,         // (N,13)
    int N)
{
    __shared__ float sred[4][16][68];   // wave-private layer-2 scratch

    const int tid  = threadIdx.x;
    const int wave = tid >> 6;
    const int lane = tid & 63;
    const int mq   = lane >> 4;
    const int o    = lane & 15;
    const float inv1 = 0.08838834764831843f;  // 1/sqrt(128)

    // ---- one-time: resident B fragments (bf16, 48 VGPR) ----
    bf16x8 bS0[4], bS1[4], bV[4];
    #pragma unroll
    for (int kb = 0; kb < 4; ++kb) {
        #pragma unroll
        for (int j = 0; j < 8; ++j) {
            const int k = kb * 32 + mq * 8 + j;
            bS0[kb][j] = f2bf(W1s[k * 32 + o]);
            bS1[kb][j] = f2bf(W1s[k * 32 + 16 + o]);
            bV [kb][j] = f2bf(W1v[k * 16 + o]);
        }
    }
    // ---- one-time: layer-2 weights (fp32, per-lane) ----
    float wcr[16];
    #pragma unroll
    for (int j = 0; j < 16; ++j)
        wcr[j] = (o < 10) ? W2s[j * 10 + o] : W2v[j];
    const float b2e = (o < 10) ? b2s[o] : 0.0f;
    const float b1a = b1s[o];
    const float b1b = b1s[16 + o];

    const int NT = N >> 4;                 // 6250 tiles
    const int wstride = gridDim.x << 2;
    const int wt0 = (blockIdx.x << 2) + wave;

    float4 LS[4][2], LV[4][6];

// issue loads of one kb-granule for tile at row-pointer xp
#define ISSUE_S(kb, xp)                                                      \
    do {                                                                     \
        LS[kb][0] = *(const float4*)((xp) + (kb) * 32 + mq * 8);             \
        LS[kb][1] = *(const float4*)((xp) + (kb) * 32 + mq * 8 + 4);         \
    } while (0)
#define ISSUE_V(kb, xp)                                                      \
    do {                                                                     \
        _Pragma("unroll")                                                    \
        for (int q = 0; q < 6; ++q)                                          \
            LV[kb][q] = *(const float4*)((xp) + 128 + (kb) * 96 + mq * 24 + q * 4); \
    } while (0)

// One full tile body. PF: 1 = prefetch next tile (pointer xq) into L regs.
#define TILE_BODY(PF)                                                        \
    do {                                                                     \
        f32x4 accS0 = {0.f,0.f,0.f,0.f}, accS1 = {0.f,0.f,0.f,0.f};          \
        f32x4 accV0 = {0.f,0.f,0.f,0.f}, accV1 = {0.f,0.f,0.f,0.f};          \
        f32x4 accV2 = {0.f,0.f,0.f,0.f};                                     \
        /* S phase: convert -> reissue(next tile) -> MFMA, per kb */         \
        _Pragma("unroll")                                                    \
        for (int kb = 0; kb < 4; ++kb) {                                     \
            i32x4 wv;                                                        \
            wv[0] = (int)cvtpk(LS[kb][0].x, LS[kb][0].y);                    \
            wv[1] = (int)cvtpk(LS[kb][0].z, LS[kb][0].w);                    \
            wv[2] = (int)cvtpk(LS[kb][1].x, LS[kb][1].y);                    \
            wv[3] = (int)cvtpk(LS[kb][1].z, LS[kb][1].w);                    \
            if (PF) ISSUE_S(kb, xq);                                         \
            const bf16x8 a = __builtin_bit_cast(bf16x8, wv);                 \
            accS0 = __builtin_amdgcn_mfma_f32_16x16x32_bf16(a, bS0[kb], accS0, 0, 0, 0); \
            accS1 = __builtin_amdgcn_mfma_f32_16x16x32_bf16(a, bS1[kb], accS1, 0, 0, 0); \
        }                                                                    \
        /* V phase: convert + stride-3 de-interleave -> reissue -> MFMA */   \
        _Pragma("unroll")                                                    \
        for (int kb = 0; kb < 4; ++kb) {                                     \
            unsigned p[12];                                                  \
            _Pragma("unroll")                                                \
            for (int q = 0; q < 6; ++q) {                                    \
                p[2*q]   = cvtpk(LV[kb][q].x, LV[kb][q].y);                  \
                p[2*q+1] = cvtpk(LV[kb][q].z, LV[kb][q].w);                  \
            }                                                                \
            if (PF) ISSUE_V(kb, xq);                                         \
            i32x4 w0, w1, w2;                                                \
            _Pragma("unroll")                                                \
            for (int w = 0; w < 4; ++w) {                                    \
                w0[w] = (int)__builtin_amdgcn_perm(p[3*w+1], p[3*w],   0x07060100u); \
                w1[w] = (int)__builtin_amdgcn_perm(p[3*w+2], p[3*w],   0x05040302u); \
                w2[w] = (int)__builtin_amdgcn_perm(p[3*w+2], p[3*w+1], 0x07060100u); \
            }                                                                \
            const bf16x8 a0 = __builtin_bit_cast(bf16x8, w0);                \
            const bf16x8 a1 = __builtin_bit_cast(bf16x8, w1);                \
            const bf16x8 a2 = __builtin_bit_cast(bf16x8, w2);                \
            accV0 = __builtin_amdgcn_mfma_f32_16x16x32_bf16(a0, bV[kb], accV0, 0, 0, 0); \
            accV1 = __builtin_amdgcn_mfma_f32_16x16x32_bf16(a1, bV[kb], accV1, 0, 0, 0); \
            accV2 = __builtin_amdgcn_mfma_f32_16x16x32_bf16(a2, bV[kb], accV2, 0, 0, 0); \
        }                                                                    \
        /* epilogue: lane-local silu + gating -> sred */                     \
        _Pragma("unroll")                                                    \
        for (int v = 0; v < 4; ++v) {                                        \
            const float hs = fmaf(accS0[v], inv1, b1a);                      \
            const float hg = fmaf(accS1[v], inv1, b1b);                      \
            const float s  = hs / (1.f + __expf(-hs));                       \
            const float g  = hg / (1.f + __expf(-hg));                       \
            const float gm = g * inv1;                                       \
            const int  r   = mq * 4 + v;                                     \
            sred[wave][r][o]      = s;                                       \
            sred[wave][r][16 + o] = gm * accV0[v];                           \
            sred[wave][r][32 + o] = gm * accV1[v];                           \
            sred[wave][r][48 + o] = gm * accV2[v];                           \
        }                                                                    \
        asm volatile("s_waitcnt lgkmcnt(0)" ::: "memory");                   \
        /* layer 2: lane o<13, dot-16 for rows mq, mq+4, mq+8, mq+12 */      \
        _Pragma("unroll")                                                    \
        for (int w = 0; w < 4; ++w) {                                        \
            const int r = (w << 2) + mq;                                     \
            if (o < 13) {                                                    \
                const int slot = (o < 10) ? 0 : (o - 9);                     \
                const float* sp = &sred[wave][r][slot * 16];                 \
                float sum = 0.f;                                             \
                _Pragma("unroll")                                            \
                for (int q = 0; q < 4; ++q) {                                \
                    const float4 pv = *(const float4*)(sp + q * 4);          \
                    sum = fmaf(pv.x, wcr[q * 4 + 0], sum);                   \
                    sum = fmaf(pv.y, wcr[q * 4 + 1], sum);                   \
                    sum = fmaf(pv.z, wcr[q * 4 + 2], sum);                   \
                    sum = fmaf(pv.w, wcr[q * 4 + 3], sum);                   \
                }                                                            \
                out[(size_t)(base + r) * 13 + o] = fmaf(sum, 0.25f, b2e);    \
            }                                                                \
        }                                                                    \
        asm volatile("s_waitcnt lgkmcnt(0)" ::: "memory");                   \
    } while (0)

    // ---- prologue: burst all 32 loads of tile wt0 ----
    if (wt0 < NT) {
        const float* xp = x + (size_t)((wt0 << 4) + o) * 512;
        #pragma unroll
        for (int kb = 0; kb < 4; ++kb) { ISSUE_S(kb, xp); ISSUE_V(kb, xp); }
    }

    int wt = wt0;
    // ---- main loop: every iteration has a valid next tile to prefetch ----
    for (; wt + wstride < NT; wt += wstride) {
        const int base = wt << 4;
        const float* xq = x + (size_t)(((wt + wstride) << 4) + o) * 512;
        TILE_BODY(1);
    }
    // ---- peeled final tile: no prefetch, no redundant fetch ----
    if (wt < NT) {
        const int base = wt << 4;
        const float* xq = nullptr; (void)xq;
        TILE_BODY(0);
    }
#undef ISSUE_S
#undef ISSUE_V
#undef TILE_BODY
}

extern "C" void kernel_launch(void* const* d_in, const int* in_sizes, int n_in,
                              void* d_out, int out_size, void* d_ws, size_t ws_size,
                              hipStream_t stream) {
    const float* x   = (const float*)d_in[0];
    const float* W1s = (const float*)d_in[1];
    const float* W1v = (const float*)d_in[2];
    const float* b1s = (const float*)d_in[3];
    const float* W2s = (const float*)d_in[4];
    const float* W2v = (const float*)d_in[5];
    const float* b2s = (const float*)d_in[6];
    float* outp = (float*)d_out;
    const int N = in_sizes[0] / 512;   // 100000
    nlrb_kernel<<<dim3(512), dim3(BLOCK), 0, stream>>>(
        x, W1s, W1v, b1s, W2s, W2v, b2s, outp, N);
}